// Round 1
// baseline (324.253 us; speedup 1.0000x reference)
//
#include <hip/hip_runtime.h>
#include <stdint.h>

typedef unsigned short u16;
typedef __bf16 bf16x8 __attribute__((ext_vector_type(8)));
typedef float f32x4 __attribute__((ext_vector_type(4)));

#define DEV static __device__ __forceinline__

// f32 -> bf16 round-to-nearest-even (finite inputs only)
DEV u16 f2bf(float f) {
  uint32_t u = __float_as_uint(f);
  u += 0x7fffu + ((u >> 16) & 1u);
  return (u16)(u >> 16);
}

// async global->LDS, 16B per lane; lds dest must be wave-uniform (HW adds lane*16)
DEV void g2l16(const void* g, void* l) {
  __builtin_amdgcn_global_load_lds(
      (__attribute__((address_space(1))) void*)(g),
      (__attribute__((address_space(3))) void*)(l), 16, 0, 0);
}

DEV f32x4 mfma16(bf16x8 a, bf16x8 b, f32x4 c) {
  return __builtin_amdgcn_mfma_f32_16x16x32_bf16(a, b, c, 0, 0, 0);
}

DEV bf16x8 lds_ld(const char* p) { return *(const bf16x8*)p; }

// ---------------- f32 -> bf16 cast, 4 elems/thread ----------------
__global__ __launch_bounds__(256) void cvt_kernel(const float* __restrict__ in,
                                                  u16* __restrict__ out, int n4) {
  int i = blockIdx.x * 256 + threadIdx.x;
  if (i >= n4) return;
  float4 v = ((const float4*)in)[i];
  ushort4 o;
  o.x = f2bf(v.x); o.y = f2bf(v.y); o.z = f2bf(v.z); o.w = f2bf(v.w);
  ((ushort4*)out)[i] = o;
}

// ---------------- C[M,N] = A[M,K] * B[N,K]^T + bias ----------------
// 128x128 tile, BK=64, 4 waves (2x2), gload_lds staging, XOR-swizzled LDS,
// 2-phase double buffer with one barrier per K-tile (stage -> compute -> sync).
// EPI=0: f32 out; EPI=1: bf16 out.
template<int EPI>
__global__ __launch_bounds__(256, 2) void gemm_bt(
    const u16* __restrict__ A, const u16* __restrict__ B,
    const float* __restrict__ bias, void* __restrict__ C,
    int M, int N, int K) {
  __shared__ char sm[2][32768];  // per buf: A tile [128][64] (16KB) + B tile (16KB)
  const int tid = threadIdx.x;
  const int w = tid >> 6, l = tid & 63;
  const int wr = w >> 1, wc = w & 1;
  const int bm0 = blockIdx.x * 128, bn0 = blockIdx.y * 128;
  // staging: lane covers row (base + l>>3), 16B slot; source slot pre-swizzled
  // so linear LDS write == swizzled layout (rule 21: inverse-swz source + swz read)
  const int lr = l >> 3, lsl = (l & 7) ^ lr;
  const u16* gA = A + (size_t)(bm0 + w * 32 + lr) * K + lsl * 8;
  const u16* gB = B + (size_t)(bn0 + w * 32 + lr) * K + lsl * 8;

  auto stage = [&](int t, int pp) {
    char* ba = sm[pp] + w * 32 * 128;   // wave-uniform LDS base
    char* bb = ba + 16384;
    const u16* a = gA + t * 64;
    const u16* b = gB + t * 64;
#pragma unroll
    for (int i = 0; i < 4; ++i) {
      g2l16(a + (size_t)i * 8 * K, ba + i * 8 * 128);
      g2l16(b + (size_t)i * 8 * K, bb + i * 8 * 128);
    }
  };

  f32x4 acc[4][4] = {};
  const int NT = K / 64;
  int pp = 0;
  stage(0, 0);
  __syncthreads();
  for (int t = 0; t < NT; ++t) {
    if (t + 1 < NT) stage(t + 1, pp ^ 1);  // loads fly during compute below
    const char* bufA = sm[pp];
    const char* bufB = bufA + 16384;
#pragma unroll
    for (int ks = 0; ks < 2; ++ks) {
      bf16x8 af[4], bfr[4];
#pragma unroll
      for (int i = 0; i < 4; ++i) {
        const int rowA = wr * 64 + i * 16 + (l & 15);
        const int colb = (ks * 64 + ((l >> 4) << 4)) ^ ((rowA & 7) << 4);
        af[i] = lds_ld(bufA + rowA * 128 + colb);
        const int rowB = wc * 64 + i * 16 + (l & 15);
        bfr[i] = lds_ld(bufB + rowB * 128 + colb);  // same swizzle: rowB&7 == l&7
      }
#pragma unroll
      for (int i = 0; i < 4; ++i)
#pragma unroll
        for (int j = 0; j < 4; ++j)
          acc[i][j] = mfma16(af[i], bfr[j], acc[i][j]);
    }
    __syncthreads();  // drains this iter's prefetch (vmcnt 0) AFTER compute
    pp ^= 1;
  }
  // epilogue: C/D layout col=lane&15, row=(lane>>4)*4+reg (m89-verified)
  const int cr = (l >> 4) * 4, cc = l & 15;
#pragma unroll
  for (int i = 0; i < 4; ++i) {
    const int gr = bm0 + wr * 64 + i * 16 + cr;
#pragma unroll
    for (int j = 0; j < 4; ++j) {
      const int gc = bn0 + wc * 64 + j * 16 + cc;
      const float bv = bias[gc];
#pragma unroll
      for (int r = 0; r < 4; ++r) {
        const float v = acc[i][j][r] + bv;
        if (EPI == 0) ((float*)C)[(size_t)(gr + r) * N + gc] = v;
        else          ((u16*)C)[(size_t)(gr + r) * N + gc] = f2bf(v);
      }
    }
  }
}

// ---------------- V slice of qkv -> V^T [B*H*D, S] ----------------
__global__ __launch_bounds__(256) void vtrans(const u16* __restrict__ qkv,
                                              u16* __restrict__ vT) {
  const int st = blockIdx.x, bh = blockIdx.y;
  const int b = bh >> 4, h = bh & 15;
  __shared__ char tile[8192];  // 64 s-rows x 128B, slot-swizzled
  const int t = threadIdx.x;
  const int s = t >> 2, q = t & 3;
  const u16* src = qkv + ((size_t)(b * 2048 + st * 64 + s)) * 3072 + 2048 + h * 64;
#pragma unroll
  for (int i = 0; i < 2; ++i) {
    const int slot = q + i * 4;
    uint4 v = *(const uint4*)(src + slot * 8);
    *(uint4*)(tile + s * 128 + ((slot ^ (s & 7)) * 16)) = v;
  }
  __syncthreads();
  const int d = t >> 2;
#pragma unroll
  for (int i = 0; i < 2; ++i) {
    const int ss0 = (q + i * 4) * 8;
    union { u16 v[8]; uint4 u; } pk;
#pragma unroll
    for (int k = 0; k < 8; ++k) {
      const int ss = ss0 + k;
      pk.v[k] = *(const u16*)(tile + ss * 128 + (((d >> 3) ^ (ss & 7)) * 16) + (d & 7) * 2);
    }
    *(uint4*)(vT + ((size_t)(bh * 64 + d)) * 2048 + st * 64 + ss0) = pk.u;
  }
}

// ---------------- flash attention ----------------
// grid (S/64, B*H), 256 thr. Wave w owns 16 q-rows. KVBLK=64 double-buffered.
__global__ __launch_bounds__(256, 2) void attn(const u16* __restrict__ qkv,
                                               const u16* __restrict__ vT,
                                               u16* __restrict__ ctx) {
  constexpr int S = 2048, E = 1024, NT = S / 64;
  const int qt = blockIdx.x, bh = blockIdx.y;
  const int b = bh >> 4, h = bh & 15;
  const int tid = threadIdx.x, w = tid >> 6, l = tid & 63;
  __shared__ char sm[2 * 16384 + 8192];  // K+V^T dbuf + per-wave P (16x128B each)
  char* const pb = sm + 32768 + w * 2048;

  const int ql = l & 15, kq = l >> 4;
  // Q fragments in registers (A-frag: row=l&15, k=(l>>4)*8+j)
  const size_t qoff = (size_t)(b * S + qt * 64 + w * 16 + ql) * (3 * E) + h * 64;
  const bf16x8 qf0 = *(const bf16x8*)(qkv + qoff + kq * 8);
  const bf16x8 qf1 = *(const bf16x8*)(qkv + qoff + 32 + kq * 8);

  const int lr = l >> 3, lsl = (l & 7) ^ lr;
  const u16* gK = qkv + (size_t)(b * S) * 3 * E + E + h * 64 + lsl * 8;
  const u16* gV = vT + (size_t)(bh * 64) * S + lsl * 8;

  auto stage = [&](int t, int pp) {
    char* bk = sm + pp * 16384 + w * 16 * 128;
#pragma unroll
    for (int i = 0; i < 2; ++i) {
      const int row = w * 16 + i * 8 + lr;               // K: kv-row / V^T: d-row
      g2l16(gK + (size_t)(t * 64 + row) * (3 * E), bk + i * 8 * 128);
      g2l16(gV + (size_t)row * S + t * 64, bk + 8192 + i * 8 * 128);
    }
  };

  f32x4 o[4] = {};
  float m[4], lsum[4];
#pragma unroll
  for (int r = 0; r < 4; ++r) { m[r] = -1e30f; lsum[r] = 0.f; }
  const float cexp = 0.18033688f;  // log2(e)/sqrt(64): fold scale into exp2

  int pp = 0;
  stage(0, 0);
  __syncthreads();
  for (int t = 0; t < NT; ++t) {
    if (t + 1 < NT) stage(t + 1, pp ^ 1);
    const char* bK = sm + pp * 16384;
    const char* bV = bK + 8192;
    // S = Q K^T (raw scores): sc[cb] holds cols cb*16..+15, rows kq*4..+3
    f32x4 sc[4] = {};
#pragma unroll
    for (int cb = 0; cb < 4; ++cb) {
      const int row = cb * 16 + ql;
      const int cswz = (row & 7) << 4;
      sc[cb] = mfma16(qf0, lds_ld(bK + row * 128 + ((kq << 4) ^ cswz)), sc[cb]);
      sc[cb] = mfma16(qf1, lds_ld(bK + row * 128 + ((64 + (kq << 4)) ^ cswz)), sc[cb]);
    }
    // wave-parallel online softmax (16-lane-group reduce)
    float tm[4];
#pragma unroll
    for (int r = 0; r < 4; ++r)
      tm[r] = fmaxf(fmaxf(sc[0][r], sc[1][r]), fmaxf(sc[2][r], sc[3][r]));
#pragma unroll
    for (int off = 1; off < 16; off <<= 1)
#pragma unroll
      for (int r = 0; r < 4; ++r) tm[r] = fmaxf(tm[r], __shfl_xor(tm[r], off));
    float al[4];
#pragma unroll
    for (int r = 0; r < 4; ++r) {
      const float mn = fmaxf(m[r], tm[r]);
      al[r] = exp2f(cexp * (m[r] - mn));
      m[r] = mn;
    }
    float ts[4] = {0.f, 0.f, 0.f, 0.f};
    u16 pv16[4][4];
#pragma unroll
    for (int cb = 0; cb < 4; ++cb)
#pragma unroll
      for (int r = 0; r < 4; ++r) {
        const float pv = exp2f(cexp * (sc[cb][r] - m[r]));
        ts[r] += pv;
        pv16[cb][r] = f2bf(pv);
      }
#pragma unroll
    for (int off = 1; off < 16; off <<= 1)
#pragma unroll
      for (int r = 0; r < 4; ++r) ts[r] += __shfl_xor(ts[r], off);
#pragma unroll
    for (int r = 0; r < 4; ++r) lsum[r] = lsum[r] * al[r] + ts[r];
#pragma unroll
    for (int db = 0; db < 4; ++db)
#pragma unroll
      for (int r = 0; r < 4; ++r) o[db][r] *= al[r];
    // P -> wave-private swizzled LDS (row=q-local, col=kv-local), then PV
#pragma unroll
    for (int cb = 0; cb < 4; ++cb)
#pragma unroll
      for (int r = 0; r < 4; ++r) {
        const int row = kq * 4 + r;
        const int byt = (cb * 16 + ql) * 2;
        *(u16*)(pb + row * 128 + (((byt >> 4) ^ (row & 7)) << 4) + (byt & 15)) = pv16[cb][r];
      }
#pragma unroll
    for (int ks = 0; ks < 2; ++ks) {
      const bf16x8 pf = lds_ld(pb + ql * 128 + ((ks * 64 + (kq << 4)) ^ ((ql & 7) << 4)));
#pragma unroll
      for (int db = 0; db < 4; ++db) {
        const int row = db * 16 + ql;  // V^T row = d
        const int colb = (ks * 64 + (kq << 4)) ^ ((row & 7) << 4);
        o[db] = mfma16(pf, lds_ld(bV + row * 128 + colb), o[db]);
      }
    }
    __syncthreads();
    pp ^= 1;
  }
  float inv[4];
#pragma unroll
  for (int r = 0; r < 4; ++r) inv[r] = 1.0f / lsum[r];
  u16* cp = ctx + (size_t)(b * S + qt * 64 + w * 16 + kq * 4) * E + h * 64;
#pragma unroll
  for (int db = 0; db < 4; ++db)
#pragma unroll
    for (int r = 0; r < 4; ++r)
      cp[(size_t)r * E + db * 16 + ql] = f2bf(o[db][r] * inv[r]);
}

extern "C" void kernel_launch(void* const* d_in, const int* in_sizes, int n_in,
                              void* d_out, int out_size, void* d_ws, size_t ws_size,
                              hipStream_t stream) {
  (void)in_sizes; (void)n_in; (void)out_size;
  const float* inp   = (const float*)d_in[0];
  const float* qkv_w = (const float*)d_in[1];
  const float* qkv_b = (const float*)d_in[2];
  const float* out_w = (const float*)d_in[3];
  const float* out_b = (const float*)d_in[4];
  char* ws = (char*)d_ws;
  if (ws_size < 92274688u) return;  // need ~88 MB scratch

  u16* inp_b  = (u16*)(ws);                  // 16,777,216 B  (reused as ctx later)
  u16* qkvw_b = (u16*)(ws + 16777216);       //  6,291,456 B
  u16* outw_b = (u16*)(ws + 23068672);       //  2,097,152 B
  u16* qkvo   = (u16*)(ws + 25165824);       // 50,331,648 B  [8192, 3072] bf16
  u16* vTb    = (u16*)(ws + 75497472);       // 16,777,216 B  [B*H*64, 2048] bf16
  u16* ctx    = inp_b;                       // gemm1 consumed inp_b by then

  hipLaunchKernelGGL(cvt_kernel, dim3(8192), dim3(256), 0, stream, inp, inp_b, 2097152);
  hipLaunchKernelGGL(cvt_kernel, dim3(3072), dim3(256), 0, stream, qkv_w, qkvw_b, 786432);
  hipLaunchKernelGGL(cvt_kernel, dim3(1024), dim3(256), 0, stream, out_w, outw_b, 262144);
  hipLaunchKernelGGL((gemm_bt<1>), dim3(64, 24), dim3(256), 0, stream,
                     inp_b, qkvw_b, qkv_b, (void*)qkvo, 8192, 3072, 1024);
  hipLaunchKernelGGL(vtrans, dim3(32, 64), dim3(256), 0, stream, qkvo, vTb);
  hipLaunchKernelGGL(attn, dim3(32, 64), dim3(256), 0, stream, qkvo, vTb, ctx);
  hipLaunchKernelGGL((gemm_bt<0>), dim3(64, 8), dim3(256), 0, stream,
                     ctx, outw_b, out_b, d_out, 8192, 1024, 1024);
}

// Round 2
// 223.171 us; speedup vs baseline: 1.4529x; 1.4529x over previous
//
#include <hip/hip_runtime.h>
#include <stdint.h>

typedef unsigned short u16;
typedef __bf16 bf16x8 __attribute__((ext_vector_type(8)));
typedef float f32x4 __attribute__((ext_vector_type(4)));
typedef float f32x16 __attribute__((ext_vector_type(16)));
typedef int i32x2 __attribute__((ext_vector_type(2)));

#define DEV static __device__ __forceinline__

// f32 -> bf16 round-to-nearest-even (finite inputs only)
DEV u16 f2bf(float f) {
  uint32_t u = __float_as_uint(f);
  u += 0x7fffu + ((u >> 16) & 1u);
  return (u16)(u >> 16);
}

// async global->LDS, 16B per lane; lds dest is wave-uniform base (HW adds lane*16)
DEV void g2l16(const void* g, void* l) {
  __builtin_amdgcn_global_load_lds(
      (__attribute__((address_space(1))) void*)(g),
      (__attribute__((address_space(3))) void*)(l), 16, 0, 0);
}

DEV f32x4 mfma16(bf16x8 a, bf16x8 b, f32x4 c) {
  return __builtin_amdgcn_mfma_f32_16x16x32_bf16(a, b, c, 0, 0, 0);
}
DEV f32x16 mfma32(bf16x8 a, bf16x8 b, f32x16 c) {
  return __builtin_amdgcn_mfma_f32_32x32x16_bf16(a, b, c, 0, 0, 0);
}

DEV bf16x8 lds_ld(const char* p) { return *(const bf16x8*)p; }

// pack two f32 to one u32 of 2 bf16 (lo from src0)
DEV uint32_t cvtpk(float lo, float hi) {
  uint32_t r;
  asm("v_cvt_pk_bf16_f32 %0, %1, %2" : "=v"(r) : "v"(lo), "v"(hi));
  return r;
}
// swap: a.hi-lanes <-> b.lo-lanes (T12 redistribution primitive)
DEV void pswap(uint32_t& a, uint32_t& b) {
  auto r = __builtin_amdgcn_permlane32_swap((int)a, (int)b, false, false);
  a = (uint32_t)r[0];
  b = (uint32_t)r[1];
}
DEV float xhalf_max(float x) {
  auto r = __builtin_amdgcn_permlane32_swap(__float_as_int(x), __float_as_int(x), false, false);
  return fmaxf(__int_as_float(r[0]), __int_as_float(r[1]));
}
DEV float xhalf_sum(float x) {
  auto r = __builtin_amdgcn_permlane32_swap(__float_as_int(x), __float_as_int(x), false, false);
  return __int_as_float(r[0]) + __int_as_float(r[1]);
}

// ---------------- f32 -> bf16 cast, 4 elems/thread ----------------
__global__ __launch_bounds__(256) void cvt_kernel(const float* __restrict__ in,
                                                  u16* __restrict__ out, int n4) {
  int i = blockIdx.x * 256 + threadIdx.x;
  if (i >= n4) return;
  float4 v = ((const float4*)in)[i];
  ushort4 o;
  o.x = f2bf(v.x); o.y = f2bf(v.y); o.z = f2bf(v.z); o.w = f2bf(v.w);
  ((ushort4*)out)[i] = o;
}

// ---------------- C[M,N] = A[M,K] * B[N,K]^T + bias ----------------
template<int EPI>
__global__ __launch_bounds__(256, 2) void gemm_bt(
    const u16* __restrict__ A, const u16* __restrict__ B,
    const float* __restrict__ bias, void* __restrict__ C,
    int M, int N, int K) {
  __shared__ char sm[2][32768];
  const int tid = threadIdx.x;
  const int w = tid >> 6, l = tid & 63;
  const int wr = w >> 1, wc = w & 1;
  const int bm0 = blockIdx.x * 128, bn0 = blockIdx.y * 128;
  const int lr = l >> 3, lsl = (l & 7) ^ lr;
  const u16* gA = A + (size_t)(bm0 + w * 32 + lr) * K + lsl * 8;
  const u16* gB = B + (size_t)(bn0 + w * 32 + lr) * K + lsl * 8;

  auto stage = [&](int t, int pp) {
    char* ba = sm[pp] + w * 32 * 128;
    char* bb = ba + 16384;
    const u16* a = gA + t * 64;
    const u16* b = gB + t * 64;
#pragma unroll
    for (int i = 0; i < 4; ++i) {
      g2l16(a + (size_t)i * 8 * K, ba + i * 8 * 128);
      g2l16(b + (size_t)i * 8 * K, bb + i * 8 * 128);
    }
  };

  f32x4 acc[4][4] = {};
  const int NT = K / 64;
  int pp = 0;
  stage(0, 0);
  __syncthreads();
  for (int t = 0; t < NT; ++t) {
    if (t + 1 < NT) stage(t + 1, pp ^ 1);
    const char* bufA = sm[pp];
    const char* bufB = bufA + 16384;
#pragma unroll
    for (int ks = 0; ks < 2; ++ks) {
      bf16x8 af[4], bfr[4];
#pragma unroll
      for (int i = 0; i < 4; ++i) {
        const int rowA = wr * 64 + i * 16 + (l & 15);
        const int colb = (ks * 64 + ((l >> 4) << 4)) ^ ((rowA & 7) << 4);
        af[i] = lds_ld(bufA + rowA * 128 + colb);
        const int rowB = wc * 64 + i * 16 + (l & 15);
        bfr[i] = lds_ld(bufB + rowB * 128 + colb);
      }
#pragma unroll
      for (int i = 0; i < 4; ++i)
#pragma unroll
        for (int j = 0; j < 4; ++j)
          acc[i][j] = mfma16(af[i], bfr[j], acc[i][j]);
    }
    __syncthreads();
    pp ^= 1;
  }
  const int cr = (l >> 4) * 4, cc = l & 15;
#pragma unroll
  for (int i = 0; i < 4; ++i) {
    const int gr = bm0 + wr * 64 + i * 16 + cr;
#pragma unroll
    for (int j = 0; j < 4; ++j) {
      const int gc = bn0 + wc * 64 + j * 16 + cc;
      const float bv = bias[gc];
#pragma unroll
      for (int r = 0; r < 4; ++r) {
        const float v = acc[i][j][r] + bv;
        if (EPI == 0) ((float*)C)[(size_t)(gr + r) * N + gc] = v;
        else          ((u16*)C)[(size_t)(gr + r) * N + gc] = f2bf(v);
      }
    }
  }
}

// ---------------- V slice of qkv -> V^T [B*H*D, S] ----------------
__global__ __launch_bounds__(256) void vtrans(const u16* __restrict__ qkv,
                                              u16* __restrict__ vT) {
  const int st = blockIdx.x, bh = blockIdx.y;
  const int b = bh >> 4, h = bh & 15;
  __shared__ char tile[8192];
  const int t = threadIdx.x;
  const int s = t >> 2, q = t & 3;
  const u16* src = qkv + ((size_t)(b * 2048 + st * 64 + s)) * 3072 + 2048 + h * 64;
#pragma unroll
  for (int i = 0; i < 2; ++i) {
    const int slot = q + i * 4;
    uint4 v = *(const uint4*)(src + slot * 8);
    *(uint4*)(tile + s * 128 + ((slot ^ (s & 7)) * 16)) = v;
  }
  __syncthreads();
  const int d = t >> 2;
#pragma unroll
  for (int i = 0; i < 2; ++i) {
    const int ss0 = (q + i * 4) * 8;
    union { u16 v[8]; uint4 u; } pk;
#pragma unroll
    for (int k = 0; k < 8; ++k) {
      const int ss = ss0 + k;
      pk.v[k] = *(const u16*)(tile + ss * 128 + (((d >> 3) ^ (ss & 7)) * 16) + (d & 7) * 2);
    }
    *(uint4*)(vT + ((size_t)(bh * 64 + d)) * 2048 + st * 64 + ss0) = pk.u;
  }
}

// ---------------- flash attention: swapped-QK^T 32x32 structure ----------------
// grid (S/128, B*H), 256 thr. Wave w owns 32 q-rows. KVBLK=64 double-buffered.
// S^T = mfma32(K, Q) -> lane holds P column for q=l&31 (kv over regs, T12).
// Softmax fully in-register; P->bf16 via cvt_pk + permlane32_swap; O^T = mfma32(V^T, P).
__global__ __launch_bounds__(256, 2) void attn(const u16* __restrict__ qkv,
                                               const u16* __restrict__ vT,
                                               u16* __restrict__ ctx) {
  constexpr int S = 2048, E = 1024, TE = 3072, NT = S / 64;
  const int qt = blockIdx.x, bh = blockIdx.y;
  const int b = bh >> 4, h = bh & 15;
  const int tid = threadIdx.x, w = tid >> 6, l = tid & 63;
  const int q = l & 31, hi = l >> 5;
  __shared__ char sm[2][16384];  // per buf: K tile [64][128B] | V^T tile [64][128B]

  // Q fragments (B-frag: col=l&31=q, k=(l>>5)*8+j), 4 d-blocks of 16
  const int qglob = qt * 128 + w * 32 + q;
  const u16* qp = qkv + (size_t)(b * S + qglob) * TE + h * 64 + hi * 8;
  bf16x8 qf[4];
#pragma unroll
  for (int d = 0; d < 4; ++d) qf[d] = *(const bf16x8*)(qp + d * 16);

  const int lr = l >> 3, lsl = (l & 7) ^ lr;  // pre-swizzled source slot (rule 21)
  const u16* gK = qkv + (size_t)(b * S) * TE + E + h * 64 + lsl * 8;
  const u16* gV = vT + (size_t)(bh * 64) * S + lsl * 8;

  auto stage = [&](int t, int pp) {
    char* bk = sm[pp] + w * 2048;  // wave w stages rows w*16..w*16+15 of K and V^T
#pragma unroll
    for (int i = 0; i < 2; ++i) {
      const int row = w * 16 + i * 8 + lr;
      g2l16(gK + (size_t)(t * 64 + row) * TE, bk + i * 1024);          // K rows (kv)
      g2l16(gV + (size_t)row * S + t * 64, bk + 8192 + i * 1024);      // V^T rows (d)
    }
  };

  f32x16 o0 = {}, o1 = {};
  float mr = -3e38f, lsum = 0.f;
  constexpr float cexp = 0.18033688f;  // log2(e)/sqrt(64)

  int pp = 0;
  stage(0, 0);
  __syncthreads();
  for (int t = 0; t < NT; ++t) {
    if (t + 1 < NT) stage(t + 1, pp ^ 1);
    const char* bK = sm[pp];
    const char* bV = sm[pp] + 8192;
    // S^T tiles: st0 = kv 0..31, st1 = kv 32..63 (for this 64-kv block)
    f32x16 st0 = {}, st1 = {};
    const int swz = (q & 7) << 4;
#pragma unroll
    for (int d = 0; d < 4; ++d) {
      const int slot = ((d * 2 + hi) << 4) ^ swz;
      st0 = mfma32(lds_ld(bK + q * 128 + slot), qf[d], st0);
      st1 = mfma32(lds_ld(bK + (32 + q) * 128 + slot), qf[d], st1);
    }
    // in-register max over 32 p-values, then cross-half combine
    float tmax[8];
#pragma unroll
    for (int i = 0; i < 8; ++i)
      tmax[i] = fmaxf(fmaxf(st0[2 * i], st0[2 * i + 1]),
                      fmaxf(st1[2 * i], st1[2 * i + 1]));
#pragma unroll
    for (int s2 = 4; s2 > 0; s2 >>= 1)
#pragma unroll
      for (int i = 0; i < s2; ++i) tmax[i] = fmaxf(tmax[i], tmax[i + s2]);
    const float tm = xhalf_max(tmax[0]);
    // defer-max (T13): only rescale when growth > 44 (=> p <= 2^7.94)
    if (!__all(tm - mr <= 44.0f)) {
      const float mn = fmaxf(mr, tm);
      const float al = exp2f(cexp * (mr - mn));
      mr = mn; lsum *= al;
#pragma unroll
      for (int r = 0; r < 16; ++r) { o0[r] *= al; o1[r] *= al; }
    }
    float tsum[4] = {0.f, 0.f, 0.f, 0.f};
#pragma unroll
    for (int r = 0; r < 16; ++r) { st0[r] = exp2f(cexp * (st0[r] - mr)); tsum[r & 3] += st0[r]; }
#pragma unroll
    for (int r = 0; r < 16; ++r) { st1[r] = exp2f(cexp * (st1[r] - mr)); tsum[r & 3] += st1[r]; }
    lsum += xhalf_sum((tsum[0] + tsum[1]) + (tsum[2] + tsum[3]));
    // P->bf16 B-frags in-register (T12) + PV: O^T[d][q] += V^T[d][kv] P^T[kv][q]
    auto pv = [&](const f32x16& e, int kvsub) {
      uint32_t a0 = cvtpk(e[0], e[1]), c0 = cvtpk(e[4], e[5]);
      uint32_t a1 = cvtpk(e[2], e[3]), c1 = cvtpk(e[6], e[7]);
      pswap(a0, c0); pswap(a1, c1);
      uint32_t a2 = cvtpk(e[8], e[9]), c2 = cvtpk(e[12], e[13]);
      uint32_t a3 = cvtpk(e[10], e[11]), c3 = cvtpk(e[14], e[15]);
      pswap(a2, c2); pswap(a3, c3);
      union { uint32_t u[4]; bf16x8 v; } p0, p1;
      p0.u[0] = a0; p0.u[1] = a1; p0.u[2] = c0; p0.u[3] = c1;  // kv sub 0..15
      p1.u[0] = a2; p1.u[1] = a3; p1.u[2] = c2; p1.u[3] = c3;  // kv sub 16..31
      const int s0 = ((kvsub * 4 + hi) << 4) ^ swz;
      const int s1 = ((kvsub * 4 + 2 + hi) << 4) ^ swz;
      o0 = mfma32(lds_ld(bV + q * 128 + s0), p0.v, o0);
      o0 = mfma32(lds_ld(bV + q * 128 + s1), p1.v, o0);
      o1 = mfma32(lds_ld(bV + (32 + q) * 128 + s0), p0.v, o1);
      o1 = mfma32(lds_ld(bV + (32 + q) * 128 + s1), p1.v, o1);
    };
    pv(st0, 0);
    pv(st1, 1);
    __syncthreads();
    pp ^= 1;
  }
  // epilogue: O^T reg r -> d = db*32 + (r&3) + 8*(r>>2) + 4*hi, row = qglob
  const float inv = 1.0f / lsum;
  u16* cp = ctx + (size_t)(b * S + qglob) * E + h * 64 + 4 * hi;
#pragma unroll
  for (int g = 0; g < 4; ++g) {
    ushort4 pk0, pk1;
    pk0.x = f2bf(o0[4 * g + 0] * inv); pk0.y = f2bf(o0[4 * g + 1] * inv);
    pk0.z = f2bf(o0[4 * g + 2] * inv); pk0.w = f2bf(o0[4 * g + 3] * inv);
    *(ushort4*)(cp + 8 * g) = pk0;
    pk1.x = f2bf(o1[4 * g + 0] * inv); pk1.y = f2bf(o1[4 * g + 1] * inv);
    pk1.z = f2bf(o1[4 * g + 2] * inv); pk1.w = f2bf(o1[4 * g + 3] * inv);
    *(ushort4*)(cp + 32 + 8 * g) = pk1;
  }
}

extern "C" void kernel_launch(void* const* d_in, const int* in_sizes, int n_in,
                              void* d_out, int out_size, void* d_ws, size_t ws_size,
                              hipStream_t stream) {
  (void)in_sizes; (void)n_in; (void)out_size;
  const float* inp   = (const float*)d_in[0];
  const float* qkv_w = (const float*)d_in[1];
  const float* qkv_b = (const float*)d_in[2];
  const float* out_w = (const float*)d_in[3];
  const float* out_b = (const float*)d_in[4];
  char* ws = (char*)d_ws;
  if (ws_size < 92274688u) return;  // need ~88 MB scratch

  u16* inp_b  = (u16*)(ws);                  // 16,777,216 B  (reused as ctx later)
  u16* qkvw_b = (u16*)(ws + 16777216);       //  6,291,456 B
  u16* outw_b = (u16*)(ws + 23068672);       //  2,097,152 B
  u16* qkvo   = (u16*)(ws + 25165824);       // 50,331,648 B  [8192, 3072] bf16
  u16* vTb    = (u16*)(ws + 75497472);       // 16,777,216 B  [B*H*64, 2048] bf16
  u16* ctx    = inp_b;

  hipLaunchKernelGGL(cvt_kernel, dim3(8192), dim3(256), 0, stream, inp, inp_b, 2097152);
  hipLaunchKernelGGL(cvt_kernel, dim3(3072), dim3(256), 0, stream, qkv_w, qkvw_b, 786432);
  hipLaunchKernelGGL(cvt_kernel, dim3(1024), dim3(256), 0, stream, out_w, outw_b, 262144);
  hipLaunchKernelGGL((gemm_bt<1>), dim3(64, 24), dim3(256), 0, stream,
                     inp_b, qkvw_b, qkv_b, (void*)qkvo, 8192, 3072, 1024);
  hipLaunchKernelGGL(vtrans, dim3(32, 64), dim3(256), 0, stream, qkvo, vTb);
  hipLaunchKernelGGL(attn, dim3(16, 64), dim3(256), 0, stream, qkvo, vTb, ctx);
  hipLaunchKernelGGL((gemm_bt<0>), dim3(64, 8), dim3(256), 0, stream,
                     ctx, outw_b, out_b, d_out, 8192, 1024, 1024);
}